// Round 24
// baseline (140.850 us; speedup 1.0000x reference)
//
#include <hip/hip_runtime.h>
#include <math.h>

// Problem constants
#define BATCH 4
#define SEQ   2048
#define HDIM  128
#define NHEAD 8
#define MROWS (BATCH*SEQ)    // 8192
#define QKVN  (3*NHEAD*HDIM) // 3072
#define YN    (NHEAD*HDIM)   // 1024

#define CS 0.12751744f   // (1/sqrt(128)) * log2(e)

using bfrag = __attribute__((ext_vector_type(8))) short;  // 8 bf16 (4 VGPRs)
using f32x4 = __attribute__((ext_vector_type(4))) float;
using s16x4 = __attribute__((ext_vector_type(4))) short;

__device__ __forceinline__ f32x4 mfma16(bfrag a, bfrag b, f32x4 c) {
    return __builtin_amdgcn_mfma_f32_16x16x32_bf16(a, b, c, 0, 0, 0);
}
__device__ __forceinline__ short f2bf(float f) {
    union { float f; unsigned u; } v; v.f = f;
    unsigned r = v.u + 0x7FFFu + ((v.u >> 16) & 1u);  // RNE
    return (short)(r >> 16);
}
__device__ __forceinline__ unsigned cvtpk(float lo, float hi) {
    unsigned r;
    asm("v_cvt_pk_bf16_f32 %0, %1, %2" : "=v"(r) : "v"(lo), "v"(hi));
    return r;   // bits[15:0]=bf16(lo), bits[31:16]=bf16(hi)
}
__device__ __forceinline__ void perm32swap(unsigned &x, unsigned &y) {
    asm volatile("v_permlane32_swap_b32 %0, %1" : "+v"(x), "+v"(y));
}
__device__ __forceinline__ f32x4 z4() { f32x4 z; z[0]=0.f; z[1]=0.f; z[2]=0.f; z[3]=0.f; return z; }

// In-register P redistribution (C-layout -> A-frag layout), validated attn8/10/12.
__device__ __forceinline__ void redist(const float p[4][4], bool hi16,
                                       bfrag &pa0o, bfrag &pa1o) {
    unsigned pk0[2], pk1[2], pk2[2], pk3[2];
    pk0[0] = cvtpk(p[0][0], p[0][1]); pk0[1] = cvtpk(p[0][2], p[0][3]);
    pk1[0] = cvtpk(p[1][0], p[1][1]); pk1[1] = cvtpk(p[1][2], p[1][3]);
    pk2[0] = cvtpk(p[2][0], p[2][1]); pk2[1] = cvtpk(p[2][2], p[2][3]);
    pk3[0] = cvtpk(p[3][0], p[3][1]); pk3[1] = cvtpk(p[3][2], p[3][3]);
    uint4 w0, w1;
    {
        unsigned A = pk0[0], C = pk1[0];
        perm32swap(A, C);
        unsigned A16 = __shfl_xor((int)A, 16), C16 = __shfl_xor((int)C, 16);
        w0.x = hi16 ? C16 : A;
        w0.z = hi16 ? C   : A16;
        unsigned B = pk0[1], D = pk1[1];
        perm32swap(B, D);
        unsigned B16 = __shfl_xor((int)B, 16), D16 = __shfl_xor((int)D, 16);
        w0.y = hi16 ? D16 : B;
        w0.w = hi16 ? D   : B16;
    }
    {
        unsigned E = pk2[0], G = pk3[0];
        perm32swap(E, G);
        unsigned E16 = __shfl_xor((int)E, 16), G16 = __shfl_xor((int)G, 16);
        w1.x = hi16 ? G16 : E;
        w1.z = hi16 ? G   : E16;
        unsigned F = pk2[1], H = pk3[1];
        perm32swap(F, H);
        unsigned F16 = __shfl_xor((int)F, 16), H16 = __shfl_xor((int)H, 16);
        w1.y = hi16 ? H16 : F;
        w1.w = hi16 ? H   : F16;
    }
    union { uint4 u; bfrag f; } cv0, cv1;
    cv0.u = w0; cv1.u = w1;
    pa0o = cv0.f; pa1o = cv1.f;
}

// ---------------------------------------------------------------------------
// Merged converters, all COALESCED (r20 verbatim).
// ---------------------------------------------------------------------------
__global__ __launch_bounds__(256) void conv_all(
    const float* __restrict__ x, const float* __restrict__ qkv,
    const float* __restrict__ proj, short* __restrict__ XB,
    short* __restrict__ qT, short* __restrict__ pT)
{
    __shared__ short Ls[64][72];
    const int bid = blockIdx.x, t = threadIdx.x;
    if (bid < 1024) {
        int i = (bid * 256 + t) * 4;
        float4 v = *(const float4*)(x + i);
        s16x4 o; o[0] = f2bf(v.x); o[1] = f2bf(v.y); o[2] = f2bf(v.z); o[3] = f2bf(v.w);
        *(s16x4*)(XB + i) = o;
        return;
    }
    const float* src;
    short* dst;
    int r0, c0, sc, sr;
    if (bid < 1120) {
        int b2 = bid - 1024;
        r0 = (b2 & 1) * 64;
        c0 = (b2 >> 1) * 64;
        src = qkv; dst = qT; sc = QKVN; sr = HDIM;
    } else {
        int b3 = bid - 1120;
        r0 = (b3 >> 1) * 64;
        c0 = (b3 & 1) * 64;
        src = proj; dst = pT; sc = HDIM; sr = YN;
    }
    {
        int r = t >> 2, ch = (t & 3) * 16;
        const float* sp = src + (size_t)(r0 + r) * sc + c0 + ch;
        #pragma unroll
        for (int q = 0; q < 4; ++q) {
            float4 v = *(const float4*)(sp + q * 4);
            Ls[r][ch + q * 4 + 0] = f2bf(v.x);
            Ls[r][ch + q * 4 + 1] = f2bf(v.y);
            Ls[r][ch + q * 4 + 2] = f2bf(v.z);
            Ls[r][ch + q * 4 + 3] = f2bf(v.w);
        }
    }
    __syncthreads();
    {
        int dr = t >> 2, ch = (t & 3) * 16;
        short tmp[16];
        #pragma unroll
        for (int i = 0; i < 16; ++i) tmp[i] = Ls[ch + i][dr];
        short* dp = dst + (size_t)(c0 + dr) * sr + r0 + ch;
        *(int4*)dp       = *(int4*)&tmp[0];
        *(int4*)(dp + 8) = *(int4*)&tmp[8];
    }
}

// ---------------------------------------------------------------------------
// GEMM1 (r17 verbatim): XB(bf16) @ qkv -> per-head Qh/Kh/Vh, swapped-operand
// packed stores.
// ---------------------------------------------------------------------------
__global__ __launch_bounds__(256) void gemm_qkv(
    const short* __restrict__ XB, const short* __restrict__ qkvT,
    short* __restrict__ Qh, short* __restrict__ Kh, short* __restrict__ Vh)
{
    const int t = threadIdx.x, lane = t & 63, w = t >> 6;
    const int lr = lane & 15, lg = lane >> 4;
    const int m0 = blockIdx.x * 128 + (w >> 1) * 64;
    const int n0 = blockIdx.y * 128 + (w & 1) * 64;

    f32x4 acc[4][4];
    #pragma unroll
    for (int i = 0; i < 4; ++i)
        #pragma unroll
        for (int j = 0; j < 4; ++j) acc[i][j] = z4();

    #pragma unroll
    for (int c = 0; c < 4; ++c) {
        bfrag a[4], bb[4];
        #pragma unroll
        for (int rt = 0; rt < 4; ++rt)
            a[rt] = *(const bfrag*)(XB + (size_t)(m0 + rt * 16 + lr) * 128 + c * 32 + lg * 8);
        #pragma unroll
        for (int nt = 0; nt < 4; ++nt)
            bb[nt] = *(const bfrag*)(qkvT + (size_t)(n0 + nt * 16 + lr) * 128 + c * 32 + lg * 8);
        #pragma unroll
        for (int rt = 0; rt < 4; ++rt)
            #pragma unroll
            for (int nt = 0; nt < 4; ++nt)
                acc[rt][nt] = mfma16(bb[nt], a[rt], acc[rt][nt]);   // SWAPPED
    }

    const int part = blockIdx.y >> 3, c8 = blockIdx.y & 7;
    short* dst = (part == 0) ? Qh : ((part == 1) ? Kh : Vh);
    #pragma unroll
    for (int rt = 0; rt < 4; ++rt) {
        int m = m0 + rt * 16 + lr;
        int b = m >> 11, sl = m & 2047;
        int nh = sl >> 8, s2 = (sl & 255) * 8 + c8;
        size_t rowbase = ((size_t)((b * 8 + nh) * 2048 + s2)) * 128;
        #pragma unroll
        for (int nt = 0; nt < 4; ++nt) {
            int h0 = (w & 1) * 64 + nt * 16 + lg * 4;
            uint2 pk;
            pk.x = cvtpk(acc[rt][nt][0], acc[rt][nt][1]);
            pk.y = cvtpk(acc[rt][nt][2], acc[rt][nt][3]);
            *(uint2*)(dst + rowbase + h0) = pk;
        }
    }
}

// ---------------------------------------------------------------------------
// Transpose V per head: Vh[bn][s2][d] -> Vt[bn][d][s2]. (r13 verbatim)
// ---------------------------------------------------------------------------
__global__ __launch_bounds__(256) void transp_v(
    const short* __restrict__ Vh, short* __restrict__ Vt)
{
    __shared__ short Ls[64][72];
    const int bn = blockIdx.z, s20 = blockIdx.x * 64, d0 = blockIdx.y * 64;
    const int t = threadIdx.x;
    const short* src = Vh + ((size_t)bn * SEQ + s20) * 128 + d0;
    {
        int r = t >> 2, ch = (t & 3) * 16;
        *(int4*)&Ls[r][ch]     = *(const int4*)(src + (size_t)r * 128 + ch);
        *(int4*)&Ls[r][ch + 8] = *(const int4*)(src + (size_t)r * 128 + ch + 8);
    }
    __syncthreads();
    {
        int dr = t >> 2, ch = (t & 3) * 16;
        short tmp[16];
        #pragma unroll
        for (int i = 0; i < 16; ++i) tmp[i] = Ls[ch + i][dr];
        short* dp = Vt + ((size_t)bn * HDIM + d0 + dr) * SEQ + s20 + ch;
        *(int4*)dp       = *(int4*)&tmp[0];
        *(int4*)(dp + 8) = *(int4*)&tmp[8];
    }
}

// ---------------------------------------------------------------------------
// attn17 = attn15 with T4 counted-vmcnt barriers (only change):
// Per-wave VMEM queue entering step s (after drained prologue, by induction):
//   [V(s):4, K(s+1):4 (issued at step top)]
//  - B2 (pre-PV):  needs only V(s) -> vmcnt(4) if s<tile else vmcnt(0),
//    then raw s_barrier. K(s+1) stays IN FLIGHT across B2 (the old
//    __syncthreads drained it half a step early).
//  - B1 (post-PV): needs K(s+1) before next step's cross-wave QK^T reads
//    -> vmcnt(0) + s_barrier. K(s+1) gains the whole PV phase of slack.
// Every cross-wave visibility edge still crosses a barrier after the
// owning wave's own-writes drain => race-free by construction.
// sched_barrier(0) after each barrier (rule #18).
// ---------------------------------------------------------------------------
__global__ __launch_bounds__(256) void attn17(
    const short* __restrict__ Qh, const short* __restrict__ Kh,
    const short* __restrict__ Vt, short* __restrict__ Y)
{
    __shared__ __align__(16) short Kls[2][64 * 128];   // 32 KB (dbuf)
    __shared__ __align__(16) short Vls[128 * 64];      // 16 KB (single)

    const int t = threadIdx.x, lane = t & 63, w = t >> 6;
    const int lr = lane & 15, lg = lane >> 4;

    const int g  = blockIdx.x;        // 0..1023
    const int bn = g & 31;            // head id; bn%8 == g%8 (XCD affinity)
    const int tile = 31 - (g >> 5);   // 64-row q-tile, work-descending
    const int b  = bn >> 3, n = bn & 7;
    const int q0 = tile * 64 + w * 16;

    const short* Qb = Qh + (size_t)bn * SEQ * HDIM;
    const short* Kb = Kh + (size_t)bn * SEQ * HDIM;
    const short* Vb = Vt + (size_t)bn * HDIM * SEQ;

    auto stageK = [&](int buf, int k0) {
        #pragma unroll
        for (int i = 0; i < 4; ++i) {
            const int q = w * 4 + i;
            const int rowK = q * 4 + (lane >> 4);
            const short* src = Kb + (size_t)(k0 + rowK) * 128 + (((lane & 15) ^ (rowK & 7)) * 8);
            __builtin_amdgcn_global_load_lds(
                (const __attribute__((address_space(1))) unsigned int*)src,
                (__attribute__((address_space(3))) unsigned int*)&Kls[buf][q * 512 + lane * 8],
                16, 0, 0);
        }
    };
    auto stageV = [&](int k0) {
        #pragma unroll
        for (int i = 0; i < 4; ++i) {
            const int q = w * 4 + i;
            const int d = q * 8 + (lane >> 3);
            const short* src = Vb + (size_t)d * SEQ + k0 + (((lane & 7) ^ (d & 7)) * 8);
            __builtin_amdgcn_global_load_lds(
                (const __attribute__((address_space(1))) unsigned int*)src,
                (__attribute__((address_space(3))) unsigned int*)&Vls[q * 512 + lane * 8],
                16, 0, 0);
        }
    };

    const int sw = lr & 7;
    const bool hi16 = (lg & 1);

    bfrag ones;
    #pragma unroll
    for (int k = 0; k < 8; ++k) ones[k] = (short)0x3F80;   // bf16 1.0

    bfrag qf[4];
    #pragma unroll
    for (int c = 0; c < 4; ++c)
        qf[c] = *(const bfrag*)(Qb + (size_t)(q0 + lr) * 128 + c * 32 + lg * 8);

    float mcs = -1.0e30f;         // per-lane: q = q0 + lr
    f32x4 l4 = z4();              // C-layout row-sums
    f32x4 o[8];
    #pragma unroll
    for (int dt = 0; dt < 8; ++dt) o[dt] = z4();

    stageK(0, 0);
    stageV(0);
    __syncthreads();   // prologue: full drain (step-0 K and V staged)

    for (int s = 0; s <= tile; ++s) {
        const int cur = s & 1;
        const int k0 = s * 64;
        if (s < tile) stageK(cur ^ 1, k0 + 64);   // K prefetch; in flight past B2

        f32x4 sA[4];
        #pragma unroll
        for (int kt = 0; kt < 4; ++kt) sA[kt] = z4();
        const int ktend = (s == tile) ? (w + 1) : 4;
        __builtin_amdgcn_s_setprio(1);
        #pragma unroll
        for (int kt = 0; kt < 4; ++kt) {
            if (kt < ktend) {   // wave-uniform
                const char* kbase = (const char*)&Kls[cur][0] + (kt * 16 + lr) * 256;
                #pragma unroll
                for (int c = 0; c < 4; ++c) {
                    bfrag kb = *(const bfrag*)(kbase + (((c * 4 + lg) ^ sw) * 16));
                    sA[kt] = mfma16(kb, qf[c], sA[kt]);   // swapped operands
                }
            }
        }
        __builtin_amdgcn_s_setprio(0);

        if (s == tile) {
            #pragma unroll
            for (int kt = 0; kt < 4; ++kt)
                #pragma unroll
                for (int j = 0; j < 4; ++j)
                    if (kt * 16 + lg * 4 + j > w * 16 + lr)
                        sA[kt][j] = -3.0e38f;
        }

        // ---- row max: max3-shaped tree + 2 cross-lg shuffles
        float mx = fmaxf(fmaxf(sA[0][0], sA[0][1]), sA[0][2]);
        mx = fmaxf(fmaxf(mx, sA[0][3]), sA[1][0]);
        mx = fmaxf(fmaxf(mx, sA[1][1]), sA[1][2]);
        mx = fmaxf(fmaxf(mx, sA[1][3]), sA[2][0]);
        mx = fmaxf(fmaxf(mx, sA[2][1]), sA[2][2]);
        mx = fmaxf(fmaxf(mx, sA[2][3]), sA[3][0]);
        mx = fmaxf(fmaxf(mx, sA[3][1]), sA[3][2]);
        mx = fmaxf(mx, sA[3][3]);
        mx = fmaxf(mx, __shfl_xor(mx, 16));
        mx = fmaxf(mx, __shfl_xor(mx, 32));
        const float pmx = mx * CS;

        // ---- T13 defer-rescale (rare)
        if (__any((pmx > mcs + 8.0f) ? 1 : 0)) {
            float nm = fmaxf(mcs, pmx);
            float al = exp2f(mcs - nm);
            mcs = nm;
            float alj[4];
            #pragma unroll
            for (int j = 0; j < 4; ++j) alj[j] = __shfl(al, lg * 4 + j);
            #pragma unroll
            for (int j = 0; j < 4; ++j) l4[j] *= alj[j];
            #pragma unroll
            for (int dt = 0; dt < 8; ++dt)
                #pragma unroll
                for (int j = 0; j < 4; ++j) o[dt][j] *= alj[j];
        }

        // ---- P = exp2(S*CS - mcs) (lane-local row)
        float p[4][4];
        #pragma unroll
        for (int kt = 0; kt < 4; ++kt)
            #pragma unroll
            for (int j = 0; j < 4; ++j)
                p[kt][j] = exp2f(sA[kt][j] * CS - mcs);

        bfrag pa0, pa1;
        redist(p, hi16, pa0, pa1);

        // ---- l via P*ones MFMA (C-layout, matrix pipe)
        l4 = mfma16(pa0, ones, mfma16(pa1, ones, l4));

        // ---- B2: wait own V(s) writes only (K(s+1) stays in flight), barrier
        if (s < tile) asm volatile("s_waitcnt vmcnt(4)" ::: "memory");
        else          asm volatile("s_waitcnt vmcnt(0)" ::: "memory");
        __builtin_amdgcn_s_barrier();
        __builtin_amdgcn_sched_barrier(0);

        // ---- PV from single Vls
        __builtin_amdgcn_s_setprio(1);
        #pragma unroll
        for (int dt = 0; dt < 8; ++dt) {
            const char* vbase = (const char*)&Vls[0] + (dt * 16 + lr) * 128;
            bfrag vb0 = *(const bfrag*)(vbase + ((lg ^ sw) * 16));
            bfrag vb1 = *(const bfrag*)(vbase + (((4 + lg) ^ sw) * 16));
            o[dt] = mfma16(pa0, vb0, o[dt]);
            o[dt] = mfma16(pa1, vb1, o[dt]);
        }
        __builtin_amdgcn_s_setprio(0);

        // ---- B1: drain K(s+1) (gained PV-phase of slack), barrier
        asm volatile("s_waitcnt vmcnt(0)" ::: "memory");
        __builtin_amdgcn_s_barrier();
        __builtin_amdgcn_sched_barrier(0);
        if (s < tile) stageV(k0 + 64);   // V(s+1); waited at B2 of step s+1
    }

    // ---- epilogue: inv directly from C-layout l4 (no shuffles)
    float inv[4];
    #pragma unroll
    for (int j = 0; j < 4; ++j) inv[j] = 1.0f / l4[j];
    #pragma unroll
    for (int j = 0; j < 4; ++j) {
        int s2 = q0 + lg * 4 + j;
        size_t yrow = (size_t)b * SEQ + n * 256 + (s2 >> 3);
        short* yp = Y + yrow * YN + (s2 & 7) * 128 + lr;
        #pragma unroll
        for (int dt = 0; dt < 8; ++dt)
            yp[dt * 16] = f2bf(o[dt][j] * inv[j]);
    }
}

// ---------------------------------------------------------------------------
// GEMM2 (r17 verbatim, swapped-operand float4 stores)
// ---------------------------------------------------------------------------
__global__ __launch_bounds__(128) void gemm_out(
    const short* __restrict__ Yb, const short* __restrict__ projT, float* __restrict__ out)
{
    const int t = threadIdx.x, lane = t & 63, w = t >> 6;   // w in 0..1
    const int lr = lane & 15, lg = lane >> 4;
    const int m0 = blockIdx.x * 16;
    const int n0 = w * 64;

    f32x4 acc[4];
    #pragma unroll
    for (int j = 0; j < 4; ++j) acc[j] = z4();

    for (int c = 0; c < 32; ++c) {
        bfrag a = *(const bfrag*)(Yb + (size_t)(m0 + lr) * YN + c * 32 + lg * 8);
        #pragma unroll
        for (int nt = 0; nt < 4; ++nt) {
            bfrag bb = *(const bfrag*)(projT + (size_t)(n0 + nt * 16 + lr) * YN + c * 32 + lg * 8);
            acc[nt] = mfma16(bb, a, acc[nt]);   // SWAPPED
        }
    }
    #pragma unroll
    for (int nt = 0; nt < 4; ++nt)
        *(f32x4*)(out + (size_t)(m0 + lr) * HDIM + n0 + nt * 16 + lg * 4) = acc[nt];
}

// ---------------------------------------------------------------------------
extern "C" void kernel_launch(void* const* d_in, const int* in_sizes, int n_in,
                              void* d_out, int out_size, void* d_ws, size_t ws_size,
                              hipStream_t stream)
{
    const float* x    = (const float*)d_in[0];  // [4,2048,128]
    const float* qkv  = (const float*)d_in[1];  // [128,3072]
    const float* proj = (const float*)d_in[2];  // [1024,128]
    float* out = (float*)d_out;                 // [8192,128]

    const size_t HEADSZ = (size_t)32 * SEQ * HDIM;        // 8,388,608 elements

    short* XB    = (short*)d_ws;                          // 2 MB
    short* qkvT  = XB    + (size_t)MROWS * HDIM;          // 0.75 MB
    short* projT = qkvT  + (size_t)QKVN * HDIM;           // 0.25 MB
    short* Qh    = projT + (size_t)HDIM * YN;             // 16 MB
    short* Kh    = Qh    + HEADSZ;                        // 16 MB
    short* Vh    = Kh    + HEADSZ;                        // 16 MB (row-major)
    short* Vtb   = Vh    + HEADSZ;                        // 16 MB (transposed)
    short* Yb    = Vtb   + HEADSZ;                        // 16 MB  (~83 MB total)

    conv_all<<<1152, 256, 0, stream>>>(x, qkv, proj, XB, qkvT, projT);
    gemm_qkv<<<dim3(MROWS / 128, QKVN / 128), 256, 0, stream>>>(XB, qkvT, Qh, Kh, Vh);
    transp_v<<<dim3(SEQ / 64, HDIM / 64, 32), 256, 0, stream>>>(Vh, Vtb);
    attn17  <<<1024, 256, 0, stream>>>(Qh, Kh, Vtb, Yb);
    gemm_out<<<MROWS / 16, 128, 0, stream>>>(Yb, projT, out);
}

// Round 25
// 139.069 us; speedup vs baseline: 1.0128x; 1.0128x over previous
//
#include <hip/hip_runtime.h>
#include <math.h>

// Problem constants
#define BATCH 4
#define SEQ   2048
#define HDIM  128
#define NHEAD 8
#define MROWS (BATCH*SEQ)    // 8192
#define QKVN  (3*NHEAD*HDIM) // 3072
#define YN    (NHEAD*HDIM)   // 1024

#define CS 0.12751744f   // (1/sqrt(128)) * log2(e)

using bfrag = __attribute__((ext_vector_type(8))) short;  // 8 bf16 (4 VGPRs)
using f32x4 = __attribute__((ext_vector_type(4))) float;
using s16x4 = __attribute__((ext_vector_type(4))) short;

__device__ __forceinline__ f32x4 mfma16(bfrag a, bfrag b, f32x4 c) {
    return __builtin_amdgcn_mfma_f32_16x16x32_bf16(a, b, c, 0, 0, 0);
}
__device__ __forceinline__ short f2bf(float f) {
    union { float f; unsigned u; } v; v.f = f;
    unsigned r = v.u + 0x7FFFu + ((v.u >> 16) & 1u);  // RNE
    return (short)(r >> 16);
}
__device__ __forceinline__ unsigned cvtpk(float lo, float hi) {
    unsigned r;
    asm("v_cvt_pk_bf16_f32 %0, %1, %2" : "=v"(r) : "v"(lo), "v"(hi));
    return r;   // bits[15:0]=bf16(lo), bits[31:16]=bf16(hi)
}
__device__ __forceinline__ void perm32swap(unsigned &x, unsigned &y) {
    asm volatile("v_permlane32_swap_b32 %0, %1" : "+v"(x), "+v"(y));
}
__device__ __forceinline__ f32x4 z4() { f32x4 z; z[0]=0.f; z[1]=0.f; z[2]=0.f; z[3]=0.f; return z; }

// In-register P redistribution (C-layout -> A-frag layout), validated attn8/10/12.
__device__ __forceinline__ void redist(const float p[4][4], bool hi16,
                                       bfrag &pa0o, bfrag &pa1o) {
    unsigned pk0[2], pk1[2], pk2[2], pk3[2];
    pk0[0] = cvtpk(p[0][0], p[0][1]); pk0[1] = cvtpk(p[0][2], p[0][3]);
    pk1[0] = cvtpk(p[1][0], p[1][1]); pk1[1] = cvtpk(p[1][2], p[1][3]);
    pk2[0] = cvtpk(p[2][0], p[2][1]); pk2[1] = cvtpk(p[2][2], p[2][3]);
    pk3[0] = cvtpk(p[3][0], p[3][1]); pk3[1] = cvtpk(p[3][2], p[3][3]);
    uint4 w0, w1;
    {
        unsigned A = pk0[0], C = pk1[0];
        perm32swap(A, C);
        unsigned A16 = __shfl_xor((int)A, 16), C16 = __shfl_xor((int)C, 16);
        w0.x = hi16 ? C16 : A;
        w0.z = hi16 ? C   : A16;
        unsigned B = pk0[1], D = pk1[1];
        perm32swap(B, D);
        unsigned B16 = __shfl_xor((int)B, 16), D16 = __shfl_xor((int)D, 16);
        w0.y = hi16 ? D16 : B;
        w0.w = hi16 ? D   : B16;
    }
    {
        unsigned E = pk2[0], G = pk3[0];
        perm32swap(E, G);
        unsigned E16 = __shfl_xor((int)E, 16), G16 = __shfl_xor((int)G, 16);
        w1.x = hi16 ? G16 : E;
        w1.z = hi16 ? G   : E16;
        unsigned F = pk2[1], H = pk3[1];
        perm32swap(F, H);
        unsigned F16 = __shfl_xor((int)F, 16), H16 = __shfl_xor((int)H, 16);
        w1.y = hi16 ? H16 : F;
        w1.w = hi16 ? H   : F16;
    }
    union { uint4 u; bfrag f; } cv0, cv1;
    cv0.u = w0; cv1.u = w1;
    pa0o = cv0.f; pa1o = cv1.f;
}

// ---------------------------------------------------------------------------
// Merged converters, all COALESCED (one launch):
//  blocks [0,1024):     x f32 -> XB bf16 (straight convert)
//  blocks [1024,1120):  qkv [128][3072] f32 -> qkvT [3072][128] bf16
//  blocks [1120,1152):  proj [1024][128] f32 -> projT [128][1024] bf16
// ---------------------------------------------------------------------------
__global__ __launch_bounds__(256) void conv_all(
    const float* __restrict__ x, const float* __restrict__ qkv,
    const float* __restrict__ proj, short* __restrict__ XB,
    short* __restrict__ qT, short* __restrict__ pT)
{
    __shared__ short Ls[64][72];
    const int bid = blockIdx.x, t = threadIdx.x;
    if (bid < 1024) {
        int i = (bid * 256 + t) * 4;
        float4 v = *(const float4*)(x + i);
        s16x4 o; o[0] = f2bf(v.x); o[1] = f2bf(v.y); o[2] = f2bf(v.z); o[3] = f2bf(v.w);
        *(s16x4*)(XB + i) = o;
        return;
    }
    const float* src;
    short* dst;
    int r0, c0, sc, sr;
    if (bid < 1120) {
        int b2 = bid - 1024;
        r0 = (b2 & 1) * 64;
        c0 = (b2 >> 1) * 64;
        src = qkv; dst = qT; sc = QKVN; sr = HDIM;
    } else {
        int b3 = bid - 1120;
        r0 = (b3 >> 1) * 64;
        c0 = (b3 & 1) * 64;
        src = proj; dst = pT; sc = HDIM; sr = YN;
    }
    {
        int r = t >> 2, ch = (t & 3) * 16;
        const float* sp = src + (size_t)(r0 + r) * sc + c0 + ch;
        #pragma unroll
        for (int q = 0; q < 4; ++q) {
            float4 v = *(const float4*)(sp + q * 4);
            Ls[r][ch + q * 4 + 0] = f2bf(v.x);
            Ls[r][ch + q * 4 + 1] = f2bf(v.y);
            Ls[r][ch + q * 4 + 2] = f2bf(v.z);
            Ls[r][ch + q * 4 + 3] = f2bf(v.w);
        }
    }
    __syncthreads();
    {
        int dr = t >> 2, ch = (t & 3) * 16;
        short tmp[16];
        #pragma unroll
        for (int i = 0; i < 16; ++i) tmp[i] = Ls[ch + i][dr];
        short* dp = dst + (size_t)(c0 + dr) * sr + r0 + ch;
        *(int4*)dp       = *(int4*)&tmp[0];
        *(int4*)(dp + 8) = *(int4*)&tmp[8];
    }
}

// ---------------------------------------------------------------------------
// GEMM1: XB(bf16) @ qkv -> per-head Qh/Kh/Vh[(b*8+n)*2048 + s2][h],
// swapped-operand packed stores (16 x 8B cvt_pk stores/thread).
// ---------------------------------------------------------------------------
__global__ __launch_bounds__(256) void gemm_qkv(
    const short* __restrict__ XB, const short* __restrict__ qkvT,
    short* __restrict__ Qh, short* __restrict__ Kh, short* __restrict__ Vh)
{
    const int t = threadIdx.x, lane = t & 63, w = t >> 6;
    const int lr = lane & 15, lg = lane >> 4;
    const int m0 = blockIdx.x * 128 + (w >> 1) * 64;
    const int n0 = blockIdx.y * 128 + (w & 1) * 64;

    f32x4 acc[4][4];
    #pragma unroll
    for (int i = 0; i < 4; ++i)
        #pragma unroll
        for (int j = 0; j < 4; ++j) acc[i][j] = z4();

    #pragma unroll
    for (int c = 0; c < 4; ++c) {
        bfrag a[4], bb[4];
        #pragma unroll
        for (int rt = 0; rt < 4; ++rt)
            a[rt] = *(const bfrag*)(XB + (size_t)(m0 + rt * 16 + lr) * 128 + c * 32 + lg * 8);
        #pragma unroll
        for (int nt = 0; nt < 4; ++nt)
            bb[nt] = *(const bfrag*)(qkvT + (size_t)(n0 + nt * 16 + lr) * 128 + c * 32 + lg * 8);
        #pragma unroll
        for (int rt = 0; rt < 4; ++rt)
            #pragma unroll
            for (int nt = 0; nt < 4; ++nt)
                acc[rt][nt] = mfma16(bb[nt], a[rt], acc[rt][nt]);   // SWAPPED
    }

    const int part = blockIdx.y >> 3, c8 = blockIdx.y & 7;
    short* dst = (part == 0) ? Qh : ((part == 1) ? Kh : Vh);
    #pragma unroll
    for (int rt = 0; rt < 4; ++rt) {
        int m = m0 + rt * 16 + lr;
        int b = m >> 11, sl = m & 2047;
        int nh = sl >> 8, s2 = (sl & 255) * 8 + c8;
        size_t rowbase = ((size_t)((b * 8 + nh) * 2048 + s2)) * 128;
        #pragma unroll
        for (int nt = 0; nt < 4; ++nt) {
            int h0 = (w & 1) * 64 + nt * 16 + lg * 4;
            uint2 pk;
            pk.x = cvtpk(acc[rt][nt][0], acc[rt][nt][1]);
            pk.y = cvtpk(acc[rt][nt][2], acc[rt][nt][3]);
            *(uint2*)(dst + rowbase + h0) = pk;
        }
    }
}

// ---------------------------------------------------------------------------
// Transpose V per head: Vh[bn][s2][d] -> Vt[bn][d][s2]. LDS-tiled, coalesced.
// ---------------------------------------------------------------------------
__global__ __launch_bounds__(256) void transp_v(
    const short* __restrict__ Vh, short* __restrict__ Vt)
{
    __shared__ short Ls[64][72];
    const int bn = blockIdx.z, s20 = blockIdx.x * 64, d0 = blockIdx.y * 64;
    const int t = threadIdx.x;
    const short* src = Vh + ((size_t)bn * SEQ + s20) * 128 + d0;
    {
        int r = t >> 2, ch = (t & 3) * 16;
        *(int4*)&Ls[r][ch]     = *(const int4*)(src + (size_t)r * 128 + ch);
        *(int4*)&Ls[r][ch + 8] = *(const int4*)(src + (size_t)r * 128 + ch + 8);
    }
    __syncthreads();
    {
        int dr = t >> 2, ch = (t & 3) * 16;
        short tmp[16];
        #pragma unroll
        for (int i = 0; i < 16; ++i) tmp[i] = Ls[ch + i][dr];
        short* dp = Vt + ((size_t)bn * HDIM + d0 + dr) * SEQ + s20 + ch;
        *(int4*)dp       = *(int4*)&tmp[0];
        *(int4*)(dp + 8) = *(int4*)&tmp[8];
    }
}

// ---------------------------------------------------------------------------
// attn15 (measured best — 77.7 us): race-free single-buffered V, K dbuf,
// 48 KB LDS -> 3 blocks/CU; 1024 single-tile blocks work-descending,
// XCD-affine; 2 barriers/step (B2 makes stageV writes visible before PV;
// B1 frees Vls after PV). Static kt, swapped QK^T in-reg softmax, in-reg P
// redistribution, l via P*ones MFMA, max3 row-max, T13 defer-rescale.
// ---------------------------------------------------------------------------
__global__ __launch_bounds__(256) void attn15(
    const short* __restrict__ Qh, const short* __restrict__ Kh,
    const short* __restrict__ Vt, short* __restrict__ Y)
{
    __shared__ __align__(16) short Kls[2][64 * 128];   // 32 KB (dbuf)
    __shared__ __align__(16) short Vls[128 * 64];      // 16 KB (single)

    const int t = threadIdx.x, lane = t & 63, w = t >> 6;
    const int lr = lane & 15, lg = lane >> 4;

    const int g  = blockIdx.x;        // 0..1023
    const int bn = g & 31;            // head id; bn%8 == g%8 (XCD affinity)
    const int tile = 31 - (g >> 5);   // 64-row q-tile, work-descending
    const int b  = bn >> 3, n = bn & 7;
    const int q0 = tile * 64 + w * 16;

    const short* Qb = Qh + (size_t)bn * SEQ * HDIM;
    const short* Kb = Kh + (size_t)bn * SEQ * HDIM;
    const short* Vb = Vt + (size_t)bn * HDIM * SEQ;

    auto stageK = [&](int buf, int k0) {
        #pragma unroll
        for (int i = 0; i < 4; ++i) {
            const int q = w * 4 + i;
            const int rowK = q * 4 + (lane >> 4);
            const short* src = Kb + (size_t)(k0 + rowK) * 128 + (((lane & 15) ^ (rowK & 7)) * 8);
            __builtin_amdgcn_global_load_lds(
                (const __attribute__((address_space(1))) unsigned int*)src,
                (__attribute__((address_space(3))) unsigned int*)&Kls[buf][q * 512 + lane * 8],
                16, 0, 0);
        }
    };
    auto stageV = [&](int k0) {
        #pragma unroll
        for (int i = 0; i < 4; ++i) {
            const int q = w * 4 + i;
            const int d = q * 8 + (lane >> 3);
            const short* src = Vb + (size_t)d * SEQ + k0 + (((lane & 7) ^ (d & 7)) * 8);
            __builtin_amdgcn_global_load_lds(
                (const __attribute__((address_space(1))) unsigned int*)src,
                (__attribute__((address_space(3))) unsigned int*)&Vls[q * 512 + lane * 8],
                16, 0, 0);
        }
    };

    const int sw = lr & 7;
    const bool hi16 = (lg & 1);

    bfrag ones;
    #pragma unroll
    for (int k = 0; k < 8; ++k) ones[k] = (short)0x3F80;   // bf16 1.0

    bfrag qf[4];
    #pragma unroll
    for (int c = 0; c < 4; ++c)
        qf[c] = *(const bfrag*)(Qb + (size_t)(q0 + lr) * 128 + c * 32 + lg * 8);

    float mcs = -1.0e30f;         // per-lane: q = q0 + lr
    f32x4 l4 = z4();              // C-layout row-sums
    f32x4 o[8];
    #pragma unroll
    for (int dt = 0; dt < 8; ++dt) o[dt] = z4();

    stageV(0);
    stageK(0, 0);
    __syncthreads();   // prologue: step-0 K and V staged (own vmcnt drained)

    for (int s = 0; s <= tile; ++s) {
        const int cur = s & 1;
        const int k0 = s * 64;
        if (s < tile) stageK(cur ^ 1, k0 + 64);   // K prefetch, spans this step

        f32x4 sA[4];
        #pragma unroll
        for (int kt = 0; kt < 4; ++kt) sA[kt] = z4();
        const int ktend = (s == tile) ? (w + 1) : 4;
        __builtin_amdgcn_s_setprio(1);
        #pragma unroll
        for (int kt = 0; kt < 4; ++kt) {
            if (kt < ktend) {   // wave-uniform
                const char* kbase = (const char*)&Kls[cur][0] + (kt * 16 + lr) * 256;
                #pragma unroll
                for (int c = 0; c < 4; ++c) {
                    bfrag kb = *(const bfrag*)(kbase + (((c * 4 + lg) ^ sw) * 16));
                    sA[kt] = mfma16(kb, qf[c], sA[kt]);   // swapped operands
                }
            }
        }
        __builtin_amdgcn_s_setprio(0);

        if (s == tile) {
            #pragma unroll
            for (int kt = 0; kt < 4; ++kt)
                #pragma unroll
                for (int j = 0; j < 4; ++j)
                    if (kt * 16 + lg * 4 + j > w * 16 + lr)
                        sA[kt][j] = -3.0e38f;
        }

        // ---- row max: max3-shaped tree + 2 cross-lg shuffles
        float mx = fmaxf(fmaxf(sA[0][0], sA[0][1]), sA[0][2]);
        mx = fmaxf(fmaxf(mx, sA[0][3]), sA[1][0]);
        mx = fmaxf(fmaxf(mx, sA[1][1]), sA[1][2]);
        mx = fmaxf(fmaxf(mx, sA[1][3]), sA[2][0]);
        mx = fmaxf(fmaxf(mx, sA[2][1]), sA[2][2]);
        mx = fmaxf(fmaxf(mx, sA[2][3]), sA[3][0]);
        mx = fmaxf(fmaxf(mx, sA[3][1]), sA[3][2]);
        mx = fmaxf(mx, sA[3][3]);
        mx = fmaxf(mx, __shfl_xor(mx, 16));
        mx = fmaxf(mx, __shfl_xor(mx, 32));
        const float pmx = mx * CS;

        // ---- T13 defer-rescale (rare)
        if (__any((pmx > mcs + 8.0f) ? 1 : 0)) {
            float nm = fmaxf(mcs, pmx);
            float al = exp2f(mcs - nm);
            mcs = nm;
            float alj[4];
            #pragma unroll
            for (int j = 0; j < 4; ++j) alj[j] = __shfl(al, lg * 4 + j);
            #pragma unroll
            for (int j = 0; j < 4; ++j) l4[j] *= alj[j];
            #pragma unroll
            for (int dt = 0; dt < 8; ++dt)
                #pragma unroll
                for (int j = 0; j < 4; ++j) o[dt][j] *= alj[j];
        }

        // ---- P = exp2(S*CS - mcs) (lane-local row)
        float p[4][4];
        #pragma unroll
        for (int kt = 0; kt < 4; ++kt)
            #pragma unroll
            for (int j = 0; j < 4; ++j)
                p[kt][j] = exp2f(sA[kt][j] * CS - mcs);

        bfrag pa0, pa1;
        redist(p, hi16, pa0, pa1);

        // ---- l via P*ones MFMA (C-layout, matrix pipe)
        l4 = mfma16(pa0, ones, mfma16(pa1, ones, l4));

        __syncthreads();   // B2: own vmcnt(0) drain per wave -> ALL stageV(s)
                           // writes visible to every wave before PV reads

        // ---- PV from single Vls
        __builtin_amdgcn_s_setprio(1);
        #pragma unroll
        for (int dt = 0; dt < 8; ++dt) {
            const char* vbase = (const char*)&Vls[0] + (dt * 16 + lr) * 128;
            bfrag vb0 = *(const bfrag*)(vbase + ((lg ^ sw) * 16));
            bfrag vb1 = *(const bfrag*)(vbase + (((4 + lg) ^ sw) * 16));
            o[dt] = mfma16(pa0, vb0, o[dt]);
            o[dt] = mfma16(pa1, vb1, o[dt]);
        }
        __builtin_amdgcn_s_setprio(0);

        __syncthreads();   // B1: all PV reads done -> Vls free
        if (s < tile) stageV(k0 + 64);   // V(s+1); drains at B2 of step s+1
    }

    // ---- epilogue: inv directly from C-layout l4 (no shuffles)
    float inv[4];
    #pragma unroll
    for (int j = 0; j < 4; ++j) inv[j] = 1.0f / l4[j];
    #pragma unroll
    for (int j = 0; j < 4; ++j) {
        int s2 = q0 + lg * 4 + j;
        size_t yrow = (size_t)b * SEQ + n * 256 + (s2 >> 3);
        short* yp = Y + yrow * YN + (s2 & 7) * 128 + lr;
        #pragma unroll
        for (int dt = 0; dt < 8; ++dt)
            yp[dt * 16] = f2bf(o[dt][j] * inv[j]);
    }
}

// ---------------------------------------------------------------------------
// GEMM2 (swapped-operand float4 stores)
// ---------------------------------------------------------------------------
__global__ __launch_bounds__(128) void gemm_out(
    const short* __restrict__ Yb, const short* __restrict__ projT, float* __restrict__ out)
{
    const int t = threadIdx.x, lane = t & 63, w = t >> 6;   // w in 0..1
    const int lr = lane & 15, lg = lane >> 4;
    const int m0 = blockIdx.x * 16;
    const int n0 = w * 64;

    f32x4 acc[4];
    #pragma unroll
    for (int j = 0; j < 4; ++j) acc[j] = z4();

    for (int c = 0; c < 32; ++c) {
        bfrag a = *(const bfrag*)(Yb + (size_t)(m0 + lr) * YN + c * 32 + lg * 8);
        #pragma unroll
        for (int nt = 0; nt < 4; ++nt) {
            bfrag bb = *(const bfrag*)(projT + (size_t)(n0 + nt * 16 + lr) * YN + c * 32 + lg * 8);
            acc[nt] = mfma16(bb, a, acc[nt]);   // SWAPPED
        }
    }
    #pragma unroll
    for (int nt = 0; nt < 4; ++nt)
        *(f32x4*)(out + (size_t)(m0 + lr) * HDIM + n0 + nt * 16 + lg * 4) = acc[nt];
}

// ---------------------------------------------------------------------------
extern "C" void kernel_launch(void* const* d_in, const int* in_sizes, int n_in,
                              void* d_out, int out_size, void* d_ws, size_t ws_size,
                              hipStream_t stream)
{
    const float* x    = (const float*)d_in[0];  // [4,2048,128]
    const float* qkv  = (const float*)d_in[1];  // [128,3072]
    const float* proj = (const float*)d_in[2];  // [1024,128]
    float* out = (float*)d_out;                 // [8192,128]

    const size_t HEADSZ = (size_t)32 * SEQ * HDIM;        // 8,388,608 elements

    short* XB    = (short*)d_ws;                          // 2 MB
    short* qkvT  = XB    + (size_t)MROWS * HDIM;          // 0.75 MB
    short* projT = qkvT  + (size_t)QKVN * HDIM;           // 0.25 MB
    short* Qh    = projT + (size_t)HDIM * YN;             // 16 MB
    short* Kh    = Qh    + HEADSZ;                        // 16 MB
    short* Vh    = Kh    + HEADSZ;                        // 16 MB (row-major)
    short* Vtb   = Vh    + HEADSZ;                        // 16 MB (transposed)
    short* Yb    = Vtb   + HEADSZ;                        // 16 MB  (~83 MB total)

    conv_all<<<1152, 256, 0, stream>>>(x, qkv, proj, XB, qkvT, projT);
    gemm_qkv<<<dim3(MROWS / 128, QKVN / 128), 256, 0, stream>>>(XB, qkvT, Qh, Kh, Vh);
    transp_v<<<dim3(SEQ / 64, HDIM / 64, 32), 256, 0, stream>>>(Vh, Vtb);
    attn15  <<<1024, 256, 0, stream>>>(Qh, Kh, Vtb, Yb);
    gemm_out<<<MROWS / 16, 128, 0, stream>>>(Yb, projT, out);
}